// Round 1
// 2641.028 us; speedup vs baseline: 1.0311x; 1.0311x over previous
//
#include <hip/hip_runtime.h>
#include <hip/hip_bf16.h>
#include <math.h>

#define D_    1152
#define H_    16
#define HD    72
#define E_    8
#define MLPH  4608
#define B_    8
#define S_    256
#define N_TOK 2048

// ---------------------------------------------------------------------------
// mod = silu(c) @ adaln_w + adaln_b      (8 x 4608)
// grid (4608/256, 8), block 256
__global__ void adaln_kernel(const float* __restrict__ c, const float* __restrict__ w,
                             const float* __restrict__ bias, float* __restrict__ mod) {
    __shared__ float sc[D_];
    int b = blockIdx.y;
    int j = blockIdx.x * 256 + threadIdx.x;
    for (int d = threadIdx.x; d < D_; d += 256) {
        float v = c[b * D_ + d];
        sc[d] = v / (1.f + __expf(-v));
    }
    __syncthreads();
    float acc = bias[j];
    for (int d = 0; d < D_; ++d)
        acc += sc[d] * w[(size_t)d * (4 * D_) + j];
    mod[b * (4 * D_) + j] = acc;
}

// ---------------------------------------------------------------------------
// LayerNorm (biased var, eps=1e-6); optionally apply adaLN modulation:
// out = ln(x) * (1 + scale_msa) + shift_msa
// grid 2048, block 256
__global__ void ln_kernel(const float* __restrict__ x, const float* __restrict__ mod,
                          float* __restrict__ out, int use_mod) {
    int n = blockIdx.x;
    int b = n / S_;
    const float* xr = x + (size_t)n * D_;
    float s = 0.f, s2 = 0.f;
    for (int d = threadIdx.x; d < D_; d += 256) {
        float v = xr[d];
        s += v; s2 += v * v;
    }
    for (int off = 32; off > 0; off >>= 1) {
        s  += __shfl_down(s,  off);
        s2 += __shfl_down(s2, off);
    }
    __shared__ float wsum[4], wsum2[4], stats[2];
    int wid = threadIdx.x >> 6, lane = threadIdx.x & 63;
    if (lane == 0) { wsum[wid] = s; wsum2[wid] = s2; }
    __syncthreads();
    if (threadIdx.x == 0) {
        float ts = 0.f, ts2 = 0.f;
        for (int i = 0; i < 4; ++i) { ts += wsum[i]; ts2 += wsum2[i]; }
        float m = ts / D_;
        float var = ts2 / D_ - m * m;
        stats[0] = m; stats[1] = rsqrtf(var + 1e-6f);
    }
    __syncthreads();
    float m = stats[0], inv = stats[1];
    for (int d = threadIdx.x; d < D_; d += 256) {
        float v = (xr[d] - m) * inv;
        if (use_mod)
            v = v * (1.f + mod[b * (4 * D_) + D_ + d]) + mod[b * (4 * D_) + d];
        out[(size_t)n * D_ + d] = v;
    }
}

// ---------------------------------------------------------------------------
// Unified fp32 GEMM, 128x128 block tile, 256 threads, 8x8 micro-tile (4+4 split),
// BK=16, k-major LDS, float4 staging, next-tile register prefetch.
//   MODE 0: dense  C[M,N] = A @ B + bias                (rowmap/outmap unused)
//   MODE 1: moe1   h1[slot] = gelu(nx[etok[p]] @ B[e] + b1[e])   rowmap=etok, outmap=eslot
//   MODE 2: moe2   eo[slot] = h1[eslot[p]] @ B[e] + b2[e]        rowmap=eslot, outmap=eslot
// N multiple of 128; K multiple of 16; M multiple of 128 (dense).
template<int MODE>
__global__ __launch_bounds__(256) void gemm128(
    const float* __restrict__ A, const float* __restrict__ Bg,
    const float* __restrict__ biasg, float* __restrict__ C,
    int M, int N, int K,
    const int* __restrict__ counts,
    const int* __restrict__ rowmap,
    const int* __restrict__ outmap) {
    int e = (MODE == 0) ? 0 : (int)blockIdx.z;
    int cnt = (MODE == 0) ? M : counts[e];
    int m0 = blockIdx.y * 128;
    if (m0 >= cnt) return;
    int n0 = blockIdx.x * 128;
    const float* B = Bg + (size_t)e * K * N;
    const float* bias = biasg + (size_t)e * N;

    __shared__ float As[16][128];
    __shared__ float Bs[16][128];

    int tid = threadIdx.x;
    int tx = tid & 15, ty = tid >> 4;

    // A staging: thread loads rows (m0+r0) and (m0+64+r0), k-quad kq4
    int r0  = tid >> 2;        // 0..63
    int kq4 = (tid & 3) * 4;   // 0,4,8,12
    const float* ap0;
    const float* ap1;
    {
        int p0 = m0 + r0, p1 = m0 + 64 + r0;
        int g0, g1;
        if (MODE == 0) { g0 = p0; g1 = p1; }
        else {
            g0 = rowmap[e * N_TOK + (p0 < cnt ? p0 : 0)];
            g1 = rowmap[e * N_TOK + (p1 < cnt ? p1 : 0)];
        }
        ap0 = A + (size_t)g0 * K + kq4;
        ap1 = A + (size_t)g1 * K + kq4;
    }
    // B staging: rows rb and rb+8, 128 contiguous cols per 32 lanes
    int rb = tid >> 5;             // 0..7
    int bc = (tid & 31) * 4;       // 0..124
    const float* bp = B + (size_t)rb * N + n0 + bc;

    float4 av0 = *(const float4*)(ap0);
    float4 av1 = *(const float4*)(ap1);
    float4 bv0 = *(const float4*)(bp);
    float4 bv1 = *(const float4*)(bp + 8 * (size_t)N);

    float acc[8][8] = {};

    for (int k0 = 0; k0 < K; k0 += 16) {
        __syncthreads();   // previous tile's readers done
        As[kq4 + 0][r0] = av0.x; As[kq4 + 1][r0] = av0.y;
        As[kq4 + 2][r0] = av0.z; As[kq4 + 3][r0] = av0.w;
        As[kq4 + 0][64 + r0] = av1.x; As[kq4 + 1][64 + r0] = av1.y;
        As[kq4 + 2][64 + r0] = av1.z; As[kq4 + 3][64 + r0] = av1.w;
        *(float4*)&Bs[rb][bc]     = bv0;
        *(float4*)&Bs[rb + 8][bc] = bv1;
        __syncthreads();
        // prefetch next K-tile into the (now dead) staging regs; hides under compute
        if (k0 + 16 < K) {
            av0 = *(const float4*)(ap0 + k0 + 16);
            av1 = *(const float4*)(ap1 + k0 + 16);
            bv0 = *(const float4*)(bp + (size_t)(k0 + 16) * N);
            bv1 = *(const float4*)(bp + (size_t)(k0 + 24) * N);
        }
#pragma unroll
        for (int k = 0; k < 16; ++k) {
            float a[8], b[8];
            *(float4*)&a[0] = *(const float4*)&As[k][ty * 4];
            *(float4*)&a[4] = *(const float4*)&As[k][64 + ty * 4];
            *(float4*)&b[0] = *(const float4*)&Bs[k][tx * 4];
            *(float4*)&b[4] = *(const float4*)&Bs[k][64 + tx * 4];
#pragma unroll
            for (int i = 0; i < 8; ++i)
#pragma unroll
                for (int j = 0; j < 8; ++j)
                    acc[i][j] += a[i] * b[j];
        }
    }

#pragma unroll
    for (int i = 0; i < 8; ++i) {
        int pr = m0 + (i >> 2) * 64 + ty * 4 + (i & 3);
        if (pr >= cnt) continue;
        size_t orow = (MODE == 0) ? (size_t)pr : (size_t)outmap[e * N_TOK + pr];
#pragma unroll
        for (int jn = 0; jn < 2; ++jn) {
            int col0 = n0 + jn * 64 + tx * 4;
            float4 o;
            float* op = &o.x;
#pragma unroll
            for (int j = 0; j < 4; ++j) {
                float v = acc[i][jn * 4 + j] + bias[col0 + j];
                if (MODE == 1) {
                    float u = 0.7978845608028654f * (v + 0.044715f * v * v * v);
                    v = 0.5f * v * (1.f + tanhf(u));
                }
                op[j] = v;
            }
            *(float4*)&C[orow * (size_t)N + col0] = o;
        }
    }
}

// ---------------------------------------------------------------------------
// Attention: one block per (q-tile of 16, head, batch). S=256 keys in 4x64 chunks.
__global__ __launch_bounds__(256) void attn_kernel(const float* __restrict__ qkv,
                                                   float* __restrict__ o) {
    int qt = blockIdx.x;  // 0..15
    int hh = blockIdx.y;  // 0..15
    int b  = blockIdx.z;  // 0..7
    __shared__ float qs[16][HD];
    __shared__ float kv[64][73];
    __shared__ float sc[16][256];
    __shared__ float rows[16];
    int tid = threadIdx.x;

    for (int i = tid; i < 16 * HD; i += 256) {
        int qi = i / HD, dd = i % HD;
        int n = b * S_ + qt * 16 + qi;
        qs[qi][dd] = qkv[(size_t)n * 3456 + hh * HD + dd];
    }
    int jj = tid & 63;
    int qg = tid >> 6;  // 0..3
    for (int c = 0; c < 4; ++c) {
        for (int i = tid; i < 64 * HD; i += 256) {
            int j = i / HD, dd = i % HD;
            int n = b * S_ + c * 64 + j;
            kv[j][dd] = qkv[(size_t)n * 3456 + D_ + hh * HD + dd];
        }
        __syncthreads();
#pragma unroll
        for (int qq = 0; qq < 4; ++qq) {
            int qi = qg * 4 + qq;
            float acc = 0.f;
            for (int dd = 0; dd < HD; ++dd) acc += qs[qi][dd] * kv[jj][dd];
            sc[qi][c * 64 + jj] = acc * 0.11785113019775793f;  // 72^-0.5
        }
        __syncthreads();
    }
    if (tid < 16) {
        float m = -1e30f;
        for (int j = 0; j < 256; ++j) m = fmaxf(m, sc[tid][j]);
        float s = 0.f;
        for (int j = 0; j < 256; ++j) {
            float e = __expf(sc[tid][j] - m);
            sc[tid][j] = e; s += e;
        }
        rows[tid] = s;
    }
    __syncthreads();
    float acc[5] = {0.f, 0.f, 0.f, 0.f, 0.f};
    for (int c = 0; c < 4; ++c) {
        for (int i = tid; i < 64 * HD; i += 256) {
            int j = i / HD, dd = i % HD;
            int n = b * S_ + c * 64 + j;
            kv[j][dd] = qkv[(size_t)n * 3456 + 2 * D_ + hh * HD + dd];
        }
        __syncthreads();
#pragma unroll
        for (int oi = 0; oi < 5; ++oi) {
            int oidx = oi * 256 + tid;
            if (oidx < 16 * HD) {
                int qi = oidx / HD, dd = oidx % HD;
                float a = acc[oi];
                for (int j = 0; j < 64; ++j) a += sc[qi][c * 64 + j] * kv[j][dd];
                acc[oi] = a;
            }
        }
        __syncthreads();
    }
    for (int oi = 0; oi < 5; ++oi) {
        int oidx = oi * 256 + tid;
        if (oidx < 16 * HD) {
            int qi = oidx / HD, dd = oidx % HD;
            int n = b * S_ + qt * 16 + qi;
            o[(size_t)n * D_ + hh * HD + dd] = acc[oi] / rows[qi];
        }
    }
}

// ---------------------------------------------------------------------------
// xa = x + gate_msa * o2
__global__ void residual1(const float* __restrict__ x, const float* __restrict__ o2,
                          const float* __restrict__ mod, float* __restrict__ xa) {
    int i = blockIdx.x * 256 + threadIdx.x;
    int n = i / D_, d = i % D_;
    int b = n / S_;
    xa[i] = x[i] + mod[b * (4 * D_) + 2 * D_ + d] * o2[i];
}

// ---------------------------------------------------------------------------
// Router: logits = nx @ gate_w + gate_b; top-2 + softmax; build expert lists.
// grid 2048, block 64 (one wave per token)
__global__ void router_kernel(const float* __restrict__ nx, const float* __restrict__ gw,
                              const float* __restrict__ gb, int* __restrict__ counts,
                              int* __restrict__ etok, int* __restrict__ eslot,
                              int* __restrict__ tslot, float* __restrict__ tscore) {
    int n = blockIdx.x;
    int lane = threadIdx.x;
    float acc[E_] = {};
    for (int d = lane; d < D_; d += 64) {
        float v = nx[(size_t)n * D_ + d];
#pragma unroll
        for (int e = 0; e < E_; ++e) acc[e] += v * gw[d * E_ + e];
    }
#pragma unroll
    for (int e = 0; e < E_; ++e)
        for (int off = 32; off > 0; off >>= 1) acc[e] += __shfl_down(acc[e], off);
    if (lane == 0) {
        float lg[E_];
#pragma unroll
        for (int e = 0; e < E_; ++e) lg[e] = acc[e] + gb[e];
        int i0 = 0;
        for (int e = 1; e < E_; ++e) if (lg[e] > lg[i0]) i0 = e;
        int i1 = -1;
        for (int e = 0; e < E_; ++e) {
            if (e == i0) continue;
            if (i1 < 0 || lg[e] > lg[i1]) i1 = e;
        }
        float e1 = __expf(lg[i1] - lg[i0]);
        float p0 = 1.f / (1.f + e1), p1 = e1 / (1.f + e1);
        int p, slot;
        p = atomicAdd(&counts[i0], 1);
        slot = atomicAdd(&counts[8], 1);
        etok[i0 * N_TOK + p] = n; eslot[i0 * N_TOK + p] = slot;
        tslot[n * 2 + 0] = slot; tscore[n * 2 + 0] = p0;
        p = atomicAdd(&counts[i1], 1);
        slot = atomicAdd(&counts[8], 1);
        etok[i1 * N_TOK + p] = n; eslot[i1 * N_TOK + p] = slot;
        tslot[n * 2 + 1] = slot; tscore[n * 2 + 1] = p1;
    }
}

// ---------------------------------------------------------------------------
// out = xa + gate_mlp * (s0*eo[slot0] + s1*eo[slot1])
__global__ void combine_kernel(const float* __restrict__ xa, const float* __restrict__ eo,
                               const float* __restrict__ mod, const int* __restrict__ tslot,
                               const float* __restrict__ tscore, float* __restrict__ out) {
    int i = blockIdx.x * 256 + threadIdx.x;
    int n = i / D_, d = i % D_, b = n / S_;
    int s0 = tslot[n * 2 + 0], s1 = tslot[n * 2 + 1];
    float moe = tscore[n * 2 + 0] * eo[(size_t)s0 * D_ + d] +
                tscore[n * 2 + 1] * eo[(size_t)s1 * D_ + d];
    out[i] = xa[i] + mod[b * (4 * D_) + 3 * D_ + d] * moe;
}

__global__ void zero_counts(int* counts) {
    if (threadIdx.x < 16) counts[threadIdx.x] = 0;
}

// ---------------------------------------------------------------------------
extern "C" void kernel_launch(void* const* d_in, const int* in_sizes, int n_in,
                              void* d_out, int out_size, void* d_ws, size_t ws_size,
                              hipStream_t stream) {
    (void)in_sizes; (void)n_in; (void)out_size; (void)ws_size;
    const float* x       = (const float*)d_in[0];
    const float* c       = (const float*)d_in[1];
    const float* qkv_w   = (const float*)d_in[2];
    const float* qkv_b   = (const float*)d_in[3];
    const float* proj_w  = (const float*)d_in[4];
    const float* proj_b  = (const float*)d_in[5];
    const float* adaln_w = (const float*)d_in[6];
    const float* adaln_b = (const float*)d_in[7];
    const float* gate_w  = (const float*)d_in[8];
    const float* gate_b  = (const float*)d_in[9];
    const float* w1      = (const float*)d_in[10];
    const float* b1      = (const float*)d_in[11];
    const float* w2      = (const float*)d_in[12];
    const float* b2      = (const float*)d_in[13];

    float* ws = (float*)d_ws;
    // region plan (floats), with overlay: h1 reuses qkv/attn_o/o2 space
    float* mod  = ws;                         //      36864
    float* xa   = ws + 36864;                 //  2,359,296
    float* buf1 = ws + 2396160;               //  2,359,296  (h, later nx)
    float* qkvb = ws + 4755456;               //  7,077,888
    float* atto = ws + 11833344;              //  2,359,296
    float* o2   = ws + 14192640;              //  2,359,296
    float* h1   = ws + 4755456;               // 18,874,368 (after qkv/atto/o2 dead)
    float* eo   = ws + 23629824;              //  4,718,592 -> ends 28,348,416
    int*   counts = (int*)(ws + 28348416);    // 16
    int*   etok   = counts + 16;              // 16384
    int*   eslot  = etok + 16384;             // 16384
    int*   tslot  = eslot + 16384;            // 4096
    float* tscore = (float*)(tslot + 4096);   // 4096

    zero_counts<<<1, 64, 0, stream>>>(counts);
    adaln_kernel<<<dim3(18, 8), 256, 0, stream>>>(c, adaln_w, adaln_b, mod);
    ln_kernel<<<N_TOK, 256, 0, stream>>>(x, mod, buf1, 1);
    gemm128<0><<<dim3(3456 / 128, N_TOK / 128), 256, 0, stream>>>(
        buf1, qkv_w, qkv_b, qkvb, N_TOK, 3456, D_, nullptr, nullptr, nullptr);
    attn_kernel<<<dim3(16, H_, B_), 256, 0, stream>>>(qkvb, atto);
    gemm128<0><<<dim3(D_ / 128, N_TOK / 128), 256, 0, stream>>>(
        atto, proj_w, proj_b, o2, N_TOK, D_, D_, nullptr, nullptr, nullptr);
    residual1<<<(N_TOK * D_) / 256, 256, 0, stream>>>(x, o2, mod, xa);
    ln_kernel<<<N_TOK, 256, 0, stream>>>(xa, nullptr, buf1, 0);
    router_kernel<<<N_TOK, 64, 0, stream>>>(buf1, gate_w, gate_b, counts, etok, eslot,
                                            tslot, tscore);
    gemm128<1><<<dim3(MLPH / 128, N_TOK / 128, E_), 256, 0, stream>>>(
        buf1, w1, b1, h1, N_TOK, MLPH, D_, counts, etok, eslot);
    gemm128<2><<<dim3(D_ / 128, N_TOK / 128, E_), 256, 0, stream>>>(
        h1, w2, b2, eo, N_TOK, D_, MLPH, counts, eslot, eslot);
    combine_kernel<<<(N_TOK * D_) / 256, 256, 0, stream>>>(xa, eo, mod, tslot, tscore,
                                                           (float*)d_out);
}